// Round 14
// baseline (143.538 us; speedup 1.0000x reference)
//
#include <hip/hip_runtime.h>
#include <hip/hip_fp16.h>

// Multi-Scale Deformable Attention forward, fp32 in/out, fp16 gather copy.
//   value:  (B=2, Len=21760, nH=8, D=32) fp32
//   loc:    (B, Q=21760, nH, L=4, P=4, 2) fp32
//   attw:   (B, Q, nH, L, P) fp32
//   out:    (B, Q, nH*D=256) fp32
// Levels: (128,128),(64,64),(32,32),(16,16), starts 0,16384,20480,21504.
//
// R14: all-round evidence says the gather is capped by a per-CU/L2
// 64B-segment fill rate (MLP x occupancy changes ~inert; -25% traffic
// -> -8%). Halve segments/tap: prologue converts value to fp16 in d_ws
// (tap row 128B->64B = ONE segment). Main kernel = R13 structure (XCD
// pinning, level-3 in LDS now 16KB, no inline asm), fp16 loads + cvt.
// Fallback: if ws_size too small, run the proven R13 fp32 kernel.

namespace {
constexpr int kB    = 2;
constexpr int kQ    = 21760;
constexpr int kHd   = 8;
constexpr int kD    = 32;
constexpr int kLen  = 21760;
constexpr int kRow  = kHd * kD;            // 256 elems per spatial position
constexpr int kQBlk = 32;                  // queries per block
constexpr int kBlksPerPair = kQ / kQBlk;   // 680
constexpr int kS3   = 21504;               // level-3 start pixel
constexpr size_t kValElems = (size_t)kB * kLen * kRow;   // 11,141,120
}

__device__ __forceinline__ void fma4(float4& a, float w, const float4 v) {
    a.x = fmaf(w, v.x, a.x);
    a.y = fmaf(w, v.y, a.y);
    a.z = fmaf(w, v.z, a.z);
    a.w = fmaf(w, v.w, a.w);
}

__device__ __forceinline__ void fma4h(float4& a, float w, const uint2 u) {
    const __half2 h0 = *reinterpret_cast<const __half2*>(&u.x);
    const __half2 h1 = *reinterpret_cast<const __half2*>(&u.y);
    const float2 f0 = __half22float2(h0);
    const float2 f1 = __half22float2(h1);
    a.x = fmaf(w, f0.x, a.x);
    a.y = fmaf(w, f0.y, a.y);
    a.z = fmaf(w, f1.x, a.z);
    a.w = fmaf(w, f1.y, a.w);
}

// ---- Prologue: value fp32 -> fp16 (8 elems/thread) ----
__global__ __launch_bounds__(256) void cvt_fp16(
    const float* __restrict__ in, __half* __restrict__ outh, int n8)
{
    const int idx = blockIdx.x * 256 + threadIdx.x;
    if (idx >= n8) return;
    const float4 a = ((const float4*)in)[idx * 2];
    const float4 b = ((const float4*)in)[idx * 2 + 1];
    __half2 h0 = __floats2half2_rn(a.x, a.y);
    __half2 h1 = __floats2half2_rn(a.z, a.w);
    __half2 h2 = __floats2half2_rn(b.x, b.y);
    __half2 h3 = __floats2half2_rn(b.z, b.w);
    uint4 u;
    u.x = *(unsigned*)&h0; u.y = *(unsigned*)&h1;
    u.z = *(unsigned*)&h2; u.w = *(unsigned*)&h3;
    ((uint4*)outh)[idx] = u;
}

// ---- Main kernel, fp16 gather path ----
__global__ __launch_bounds__(256, 6) void msda_fwd_h(
    const __half* __restrict__ vh16,
    const float* __restrict__ loc,
    const float* __restrict__ attw,
    float* __restrict__ out)
{
    const int i    = blockIdx.x;
    const int xcd  = i & 7;
    const int k    = i >> 3;
    const int b    = (k >= kBlksPerPair) ? 1 : 0;
    const int j    = k - b * kBlksPerPair;
    const int h    = xcd;

    // Preload this pair's level-3 slice (256 px * 32 ch fp16 = 16 KB).
    __shared__ __half lv3[256 * kD];
    {
        const __half* src = vh16 + ((size_t)(b * kLen + kS3)) * kRow + h * kD;
        uint2* dst = (uint2*)lv3;
        #pragma unroll
        for (int r = 0; r < 8; ++r) {
            const int idx  = r * 256 + threadIdx.x;   // 0..2047 uint2
            const int pix  = idx >> 3;
            const int part = idx & 7;
            dst[idx] = ((const uint2*)src)[pix * 64 + part];
        }
    }
    __syncthreads();

    const int qi   = threadIdx.x >> 3;     // 0..31
    const int sub  = threadIdx.x & 7;      // channel float4 slot
    const int q    = j * kQBlk + qi;
    const int g    = (b * kQ + q) * kHd + h;

    const float4* lp4 = (const float4*)(loc  + (size_t)g * 32);
    const float4* ap4 = (const float4*)(attw + (size_t)g * 16);
    // thread's base in halves
    const __half* vb = vh16 + (size_t)b * kLen * kRow + h * kD + sub * 4;

    float4 acc = make_float4(0.f, 0.f, 0.f, 0.f);

    constexpr int Hs[3] = {128, 64, 32};
    constexpr int Ws[3] = {128, 64, 32};
    constexpr int Ss[3] = {0, 16384, 20480};

    // Levels 0..2: fp16 global gather (L2-resident via XCD pinning)
    #pragma unroll
    for (int l = 0; l < 3; ++l) {
        const int W = Ws[l];
        const int H = Hs[l];
        const int S = Ss[l];

        const float4 lc0 = lp4[2 * l];
        const float4 lc1 = lp4[2 * l + 1];
        const float4 av  = ap4[l];

        const float lx[4] = {lc0.x, lc0.z, lc1.x, lc1.z};
        const float ly[4] = {lc0.y, lc0.w, lc1.y, lc1.w};
        const float aa[4] = {av.x,  av.y,  av.z,  av.w};

        #pragma unroll
        for (int p = 0; p < 4; ++p) {
            // grid_sample(align_corners=False): x = loc_x * W - 0.5
            const float x = fmaf(lx[p], (float)W, -0.5f);
            const float y = fmaf(ly[p], (float)H, -0.5f);
            const float x0f = floorf(x);
            const float y0f = floorf(y);
            const float fx = x - x0f;
            const float fy = y - y0f;
            const int   x0 = (int)x0f;
            const int   y0 = (int)y0f;
            const float a  = aa[p];

            const bool vx0 = (unsigned)x0       < (unsigned)W;
            const bool vx1 = (unsigned)(x0 + 1) < (unsigned)W;
            const bool vy0 = (unsigned)y0       < (unsigned)H;
            const bool vy1 = (unsigned)(y0 + 1) < (unsigned)H;

            const int xc0 = min(max(x0, 0),     W - 1);
            const int xc1 = min(max(x0 + 1, 0), W - 1);
            const int yc0 = min(max(y0, 0),     H - 1);
            const int yc1 = min(max(y0 + 1, 0), H - 1);

            float w00 = a * (1.f - fx) * (1.f - fy);
            float w01 = a * fx * (1.f - fy);
            float w10 = a * (1.f - fx) * fy;
            float w11 = a * fx * fy;
            w00 = (vy0 && vx0) ? w00 : 0.f;
            w01 = (vy0 && vx1) ? w01 : 0.f;
            w10 = (vy1 && vx0) ? w10 : 0.f;
            w11 = (vy1 && vx1) ? w11 : 0.f;

            const int r0 = (S + yc0 * W) * kRow;   // in halves
            const int r1 = (S + yc1 * W) * kRow;
            const uint2 v00 = *(const uint2*)(vb + r0 + xc0 * kRow);
            const uint2 v01 = *(const uint2*)(vb + r0 + xc1 * kRow);
            const uint2 v10 = *(const uint2*)(vb + r1 + xc0 * kRow);
            const uint2 v11 = *(const uint2*)(vb + r1 + xc1 * kRow);

            fma4h(acc, w00, v00);
            fma4h(acc, w01, v01);
            fma4h(acc, w10, v10);
            fma4h(acc, w11, v11);
        }
    }

    // Level 3: serve from LDS (fp16)
    {
        constexpr int W = 16, H = 16;
        const float4 lc0 = lp4[6];
        const float4 lc1 = lp4[7];
        const float4 av  = ap4[3];

        const float lx[4] = {lc0.x, lc0.z, lc1.x, lc1.z};
        const float ly[4] = {lc0.y, lc0.w, lc1.y, lc1.w};
        const float aa[4] = {av.x,  av.y,  av.z,  av.w};

        #pragma unroll
        for (int p = 0; p < 4; ++p) {
            const float x = fmaf(lx[p], (float)W, -0.5f);
            const float y = fmaf(ly[p], (float)H, -0.5f);
            const float x0f = floorf(x);
            const float y0f = floorf(y);
            const float fx = x - x0f;
            const float fy = y - y0f;
            const int   x0 = (int)x0f;
            const int   y0 = (int)y0f;
            const float a  = aa[p];

            const bool vx0 = (unsigned)x0       < (unsigned)W;
            const bool vx1 = (unsigned)(x0 + 1) < (unsigned)W;
            const bool vy0 = (unsigned)y0       < (unsigned)H;
            const bool vy1 = (unsigned)(y0 + 1) < (unsigned)H;

            const int xc0 = min(max(x0, 0),     W - 1);
            const int xc1 = min(max(x0 + 1, 0), W - 1);
            const int yc0 = min(max(y0, 0),     H - 1);
            const int yc1 = min(max(y0 + 1, 0), H - 1);

            float w00 = a * (1.f - fx) * (1.f - fy);
            float w01 = a * fx * (1.f - fy);
            float w10 = a * (1.f - fx) * fy;
            float w11 = a * fx * fy;
            w00 = (vy0 && vx0) ? w00 : 0.f;
            w01 = (vy0 && vx1) ? w01 : 0.f;
            w10 = (vy1 && vx0) ? w10 : 0.f;
            w11 = (vy1 && vx1) ? w11 : 0.f;

            const uint2* lb = (const uint2*)lv3;
            const uint2 v00 = lb[(yc0 * W + xc0) * 8 + sub];
            const uint2 v01 = lb[(yc0 * W + xc1) * 8 + sub];
            const uint2 v10 = lb[(yc1 * W + xc0) * 8 + sub];
            const uint2 v11 = lb[(yc1 * W + xc1) * 8 + sub];

            fma4h(acc, w00, v00);
            fma4h(acc, w01, v01);
            fma4h(acc, w10, v10);
            fma4h(acc, w11, v11);
        }
    }

    *(float4*)(out + ((size_t)(b * kQ + q)) * kRow + h * kD + sub * 4) = acc;
}

// ---- Fallback: R13 fp32 kernel (proven, used if ws too small) ----
__global__ __launch_bounds__(256, 4) void msda_fwd_f32(
    const float* __restrict__ value,
    const float* __restrict__ loc,
    const float* __restrict__ attw,
    float* __restrict__ out)
{
    const int i    = blockIdx.x;
    const int xcd  = i & 7;
    const int k    = i >> 3;
    const int b    = (k >= kBlksPerPair) ? 1 : 0;
    const int j    = k - b * kBlksPerPair;
    const int h    = xcd;

    __shared__ float lv3[256 * kD];        // 32 KB
    {
        const float* src = value + ((size_t)(b * kLen + kS3)) * kRow + h * kD;
        float4* dst = (float4*)lv3;
        #pragma unroll
        for (int r = 0; r < 8; ++r) {
            const int idx  = r * 256 + threadIdx.x;
            const int pix  = idx >> 3;
            const int quad = idx & 7;
            dst[idx] = *(const float4*)(src + (size_t)pix * kRow + quad * 4);
        }
    }
    __syncthreads();

    const int qi   = threadIdx.x >> 3;
    const int sub  = threadIdx.x & 7;
    const int q    = j * kQBlk + qi;
    const int g    = (b * kQ + q) * kHd + h;

    const float4* lp4 = (const float4*)(loc  + (size_t)g * 32);
    const float4* ap4 = (const float4*)(attw + (size_t)g * 16);
    const float*  vb  = value + (size_t)b * kLen * kRow + h * kD + sub * 4;

    float4 acc = make_float4(0.f, 0.f, 0.f, 0.f);

    constexpr int Hs[3] = {128, 64, 32};
    constexpr int Ws[3] = {128, 64, 32};
    constexpr int Ss[3] = {0, 16384, 20480};

    #pragma unroll
    for (int l = 0; l < 3; ++l) {
        const int W = Ws[l];
        const int H = Hs[l];
        const int S = Ss[l];

        const float4 lc0 = lp4[2 * l];
        const float4 lc1 = lp4[2 * l + 1];
        const float4 av  = ap4[l];

        const float lx[4] = {lc0.x, lc0.z, lc1.x, lc1.z};
        const float ly[4] = {lc0.y, lc0.w, lc1.y, lc1.w};
        const float aa[4] = {av.x,  av.y,  av.z,  av.w};

        #pragma unroll
        for (int p = 0; p < 4; ++p) {
            const float x = fmaf(lx[p], (float)W, -0.5f);
            const float y = fmaf(ly[p], (float)H, -0.5f);
            const float x0f = floorf(x);
            const float y0f = floorf(y);
            const float fx = x - x0f;
            const float fy = y - y0f;
            const int   x0 = (int)x0f;
            const int   y0 = (int)y0f;
            const float a  = aa[p];

            const bool vx0 = (unsigned)x0       < (unsigned)W;
            const bool vx1 = (unsigned)(x0 + 1) < (unsigned)W;
            const bool vy0 = (unsigned)y0       < (unsigned)H;
            const bool vy1 = (unsigned)(y0 + 1) < (unsigned)H;

            const int xc0 = min(max(x0, 0),     W - 1);
            const int xc1 = min(max(x0 + 1, 0), W - 1);
            const int yc0 = min(max(y0, 0),     H - 1);
            const int yc1 = min(max(y0 + 1, 0), H - 1);

            float w00 = a * (1.f - fx) * (1.f - fy);
            float w01 = a * fx * (1.f - fy);
            float w10 = a * (1.f - fx) * fy;
            float w11 = a * fx * fy;
            w00 = (vy0 && vx0) ? w00 : 0.f;
            w01 = (vy0 && vx1) ? w01 : 0.f;
            w10 = (vy1 && vx0) ? w10 : 0.f;
            w11 = (vy1 && vx1) ? w11 : 0.f;

            const int r0 = (S + yc0 * W) * kRow;
            const int r1 = (S + yc1 * W) * kRow;
            const float4 v00 = *(const float4*)(vb + r0 + xc0 * kRow);
            const float4 v01 = *(const float4*)(vb + r0 + xc1 * kRow);
            const float4 v10 = *(const float4*)(vb + r1 + xc0 * kRow);
            const float4 v11 = *(const float4*)(vb + r1 + xc1 * kRow);

            fma4(acc, w00, v00);
            fma4(acc, w01, v01);
            fma4(acc, w10, v10);
            fma4(acc, w11, v11);
        }
    }

    {
        constexpr int W = 16, H = 16;
        const float4 lc0 = lp4[6];
        const float4 lc1 = lp4[7];
        const float4 av  = ap4[3];

        const float lx[4] = {lc0.x, lc0.z, lc1.x, lc1.z};
        const float ly[4] = {lc0.y, lc0.w, lc1.y, lc1.w};
        const float aa[4] = {av.x,  av.y,  av.z,  av.w};

        #pragma unroll
        for (int p = 0; p < 4; ++p) {
            const float x = fmaf(lx[p], (float)W, -0.5f);
            const float y = fmaf(ly[p], (float)H, -0.5f);
            const float x0f = floorf(x);
            const float y0f = floorf(y);
            const float fx = x - x0f;
            const float fy = y - y0f;
            const int   x0 = (int)x0f;
            const int   y0 = (int)y0f;
            const float a  = aa[p];

            const bool vx0 = (unsigned)x0       < (unsigned)W;
            const bool vx1 = (unsigned)(x0 + 1) < (unsigned)W;
            const bool vy0 = (unsigned)y0       < (unsigned)H;
            const bool vy1 = (unsigned)(y0 + 1) < (unsigned)H;

            const int xc0 = min(max(x0, 0),     W - 1);
            const int xc1 = min(max(x0 + 1, 0), W - 1);
            const int yc0 = min(max(y0, 0),     H - 1);
            const int yc1 = min(max(y0 + 1, 0), H - 1);

            float w00 = a * (1.f - fx) * (1.f - fy);
            float w01 = a * fx * (1.f - fy);
            float w10 = a * (1.f - fx) * fy;
            float w11 = a * fx * fy;
            w00 = (vy0 && vx0) ? w00 : 0.f;
            w01 = (vy0 && vx1) ? w01 : 0.f;
            w10 = (vy1 && vx0) ? w10 : 0.f;
            w11 = (vy1 && vx1) ? w11 : 0.f;

            const float* lbase = lv3 + sub * 4;
            const float4 v00 = *(const float4*)(lbase + (yc0 * W + xc0) * kD);
            const float4 v01 = *(const float4*)(lbase + (yc0 * W + xc1) * kD);
            const float4 v10 = *(const float4*)(lbase + (yc1 * W + xc0) * kD);
            const float4 v11 = *(const float4*)(lbase + (yc1 * W + xc1) * kD);

            fma4(acc, w00, v00);
            fma4(acc, w01, v01);
            fma4(acc, w10, v10);
            fma4(acc, w11, v11);
        }
    }

    *(float4*)(out + ((size_t)(b * kQ + q)) * kRow + h * kD + sub * 4) = acc;
}

extern "C" void kernel_launch(void* const* d_in, const int* in_sizes, int n_in,
                              void* d_out, int out_size, void* d_ws, size_t ws_size,
                              hipStream_t stream) {
    const float* value = (const float*)d_in[0];
    const float* loc   = (const float*)d_in[3];
    const float* attw  = (const float*)d_in[4];
    float* out = (float*)d_out;

    const int grid = kB * kHd * kBlksPerPair;   // 10880

    if (ws_size >= kValElems * sizeof(__half)) {
        __half* vh = (__half*)d_ws;
        const int n8 = (int)(kValElems / 8);            // 1,392,640
        cvt_fp16<<<(n8 + 255) / 256, 256, 0, stream>>>(value, vh, n8);
        msda_fwd_h<<<grid, 256, 0, stream>>>(vh, loc, attw, out);
    } else {
        msda_fwd_f32<<<grid, 256, 0, stream>>>(value, loc, attw, out);
    }
}

// Round 15
// 94.400 us; speedup vs baseline: 1.5205x; 1.5205x over previous
//
#include <hip/hip_runtime.h>
#include <hip/hip_fp16.h>

// Multi-Scale Deformable Attention forward, fp32 in/out, fp16 transposed copy.
//   value:  (B=2, Len=21760, nH=8, D=32) fp32
//   loc:    (B, Q=21760, nH, L=4, P=4, 2) fp32
//   attw:   (B, Q, nH, L, P) fp32
//   out:    (B, Q, nH*D=256) fp32
// Levels: (128,128),(64,64),(32,32),(16,16), starts 0,16384,20480,21504.
//
// R15: R14 showed issue-rate bound (VALUBusy 50%, occ 72%, HBM 9%).
//  * prologue converts value to fp16 AND transposes to [b][h][pix][ch]
//    (head slice contiguous -> every L2 line fully owned by its XCD-pinned
//    head; tap row = one 64B segment).
//  * main kernel: 4 subs/thread (8 fp16 ch = 16B uint4/corner) -> halves
//    redundant per-sample math AND gather instruction count.
//  * per-element fmaf(w, half2float(h), acc) -> v_fma_mix_f32 (cvt folded).
//  * XCD pinning, level-3 in LDS (16 KB), no inline asm. f32 fallback.

namespace {
constexpr int kB    = 2;
constexpr int kQ    = 21760;
constexpr int kHd   = 8;
constexpr int kD    = 32;
constexpr int kLen  = 21760;
constexpr int kRow  = kHd * kD;            // 256 elems per spatial position
constexpr int kQBlk = 64;                  // queries per block (4 subs/thread)
constexpr int kBlksPerPair = kQ / kQBlk;   // 340
constexpr int kS3   = 21504;               // level-3 start pixel
constexpr size_t kValElems = (size_t)kB * kLen * kRow;   // 11,141,120
}

__device__ __forceinline__ void fma4(float4& a, float w, const float4 v) {
    a.x = fmaf(w, v.x, a.x);
    a.y = fmaf(w, v.y, a.y);
    a.z = fmaf(w, v.z, a.z);
    a.w = fmaf(w, v.w, a.w);
}

__device__ __forceinline__ void fma8h(float* acc, float w, uint4 u) {
    const __half* hp = (const __half*)&u;
    #pragma unroll
    for (int e = 0; e < 8; ++e)
        acc[e] = fmaf(w, __half2float(hp[e]), acc[e]);   // -> v_fma_mix_f32
}

// ---- Prologue: value fp32 [b][pix][h][ch] -> fp16 [b][h][pix][ch] ----
__global__ __launch_bounds__(256) void cvt_t(
    const float* __restrict__ in, __half* __restrict__ outh)
{
    const int t   = blockIdx.x * 256 + threadIdx.x;   // 0..2,785,279
    const int sub = t & 7;          // 4-float chunk within head row
    const int h   = (t >> 3) & 7;
    const int bp  = t >> 6;         // b*Len + pix
    const int b   = (bp >= kLen) ? 1 : 0;
    const int pix = bp - b * kLen;

    const float4 v = ((const float4*)in)[(size_t)bp * 64 + h * 8 + sub];
    __half2 h0 = __floats2half2_rn(v.x, v.y);
    __half2 h1 = __floats2half2_rn(v.z, v.w);
    uint2 u;
    u.x = *(unsigned*)&h0;
    u.y = *(unsigned*)&h1;
    ((uint2*)outh)[((size_t)(b * kHd + h) * kLen + pix) * 8 + sub] = u;
}

// ---- Main kernel: fp16 transposed gather, 4 subs/thread ----
__global__ __launch_bounds__(256, 4) void msda_fwd_h(
    const __half* __restrict__ vh,
    const float* __restrict__ loc,
    const float* __restrict__ attw,
    float* __restrict__ out)
{
    const int i    = blockIdx.x;
    const int xcd  = i & 7;
    const int k    = i >> 3;
    const int b    = (k >= kBlksPerPair) ? 1 : 0;
    const int j    = k - b * kBlksPerPair;
    const int h    = xcd;

    const char* slice = (const char*)vh + ((size_t)(b * kHd + h) * kLen) * 64;

    // Preload this pair's level-3 slice (256 px * 64 B = 16 KB) into LDS.
    __shared__ __align__(16) char lv3[256 * 64];
    {
        const uint4* src = (const uint4*)(slice + (size_t)kS3 * 64);
        uint4* dst = (uint4*)lv3;
        #pragma unroll
        for (int r = 0; r < 4; ++r)
            dst[r * 256 + threadIdx.x] = src[r * 256 + threadIdx.x];
    }
    __syncthreads();

    const int qi   = threadIdx.x >> 2;     // 0..63
    const int sub  = threadIdx.x & 3;      // 8-channel slot
    const int q    = j * kQBlk + qi;
    const int g    = (b * kQ + q) * kHd + h;

    const float4* lp4 = (const float4*)(loc  + (size_t)g * 32);
    const float4* ap4 = (const float4*)(attw + (size_t)g * 16);
    const char* vthr = slice + sub * 16;   // this thread's channel slice

    float acc[8];
    #pragma unroll
    for (int e = 0; e < 8; ++e) acc[e] = 0.f;

    constexpr int Hs[3] = {128, 64, 32};
    constexpr int Ws[3] = {128, 64, 32};
    constexpr int Ss[3] = {0, 16384, 20480};

    // Levels 0..2: global gather (L2-resident via XCD pinning)
    #pragma unroll
    for (int l = 0; l < 3; ++l) {
        const int W = Ws[l];
        const int H = Hs[l];
        const int S = Ss[l];

        const float4 lc0 = lp4[2 * l];
        const float4 lc1 = lp4[2 * l + 1];
        const float4 av  = ap4[l];

        const float lx[4] = {lc0.x, lc0.z, lc1.x, lc1.z};
        const float ly[4] = {lc0.y, lc0.w, lc1.y, lc1.w};
        const float aa[4] = {av.x,  av.y,  av.z,  av.w};

        #pragma unroll
        for (int p = 0; p < 4; ++p) {
            // grid_sample(align_corners=False): x = loc_x * W - 0.5
            const float x = fmaf(lx[p], (float)W, -0.5f);
            const float y = fmaf(ly[p], (float)H, -0.5f);
            const float x0f = floorf(x);
            const float y0f = floorf(y);
            const float fx = x - x0f;
            const float fy = y - y0f;
            const int   x0 = (int)x0f;
            const int   y0 = (int)y0f;
            const float a  = aa[p];

            const bool vx0 = (unsigned)x0       < (unsigned)W;
            const bool vx1 = (unsigned)(x0 + 1) < (unsigned)W;
            const bool vy0 = (unsigned)y0       < (unsigned)H;
            const bool vy1 = (unsigned)(y0 + 1) < (unsigned)H;

            const int xc0 = min(max(x0, 0),     W - 1);
            const int xc1 = min(max(x0 + 1, 0), W - 1);
            const int yc0 = min(max(y0, 0),     H - 1);
            const int yc1 = min(max(y0 + 1, 0), H - 1);

            float w00 = a * (1.f - fx) * (1.f - fy);
            float w01 = a * fx * (1.f - fy);
            float w10 = a * (1.f - fx) * fy;
            float w11 = a * fx * fy;
            w00 = (vy0 && vx0) ? w00 : 0.f;
            w01 = (vy0 && vx1) ? w01 : 0.f;
            w10 = (vy1 && vx0) ? w10 : 0.f;
            w11 = (vy1 && vx1) ? w11 : 0.f;

            const int r0 = (S + yc0 * W) << 6;   // bytes (64 B / pixel)
            const int r1 = (S + yc1 * W) << 6;
            const uint4 v00 = *(const uint4*)(vthr + r0 + (xc0 << 6));
            const uint4 v01 = *(const uint4*)(vthr + r0 + (xc1 << 6));
            const uint4 v10 = *(const uint4*)(vthr + r1 + (xc0 << 6));
            const uint4 v11 = *(const uint4*)(vthr + r1 + (xc1 << 6));

            fma8h(acc, w00, v00);
            fma8h(acc, w01, v01);
            fma8h(acc, w10, v10);
            fma8h(acc, w11, v11);
        }
    }

    // Level 3: serve from LDS
    {
        constexpr int W = 16, H = 16;
        const float4 lc0 = lp4[6];
        const float4 lc1 = lp4[7];
        const float4 av  = ap4[3];

        const float lx[4] = {lc0.x, lc0.z, lc1.x, lc1.z};
        const float ly[4] = {lc0.y, lc0.w, lc1.y, lc1.w};
        const float aa[4] = {av.x,  av.y,  av.z,  av.w};

        const char* lthr = lv3 + sub * 16;

        #pragma unroll
        for (int p = 0; p < 4; ++p) {
            const float x = fmaf(lx[p], (float)W, -0.5f);
            const float y = fmaf(ly[p], (float)H, -0.5f);
            const float x0f = floorf(x);
            const float y0f = floorf(y);
            const float fx = x - x0f;
            const float fy = y - y0f;
            const int   x0 = (int)x0f;
            const int   y0 = (int)y0f;
            const float a  = aa[p];

            const bool vx0 = (unsigned)x0       < (unsigned)W;
            const bool vx1 = (unsigned)(x0 + 1) < (unsigned)W;
            const bool vy0 = (unsigned)y0       < (unsigned)H;
            const bool vy1 = (unsigned)(y0 + 1) < (unsigned)H;

            const int xc0 = min(max(x0, 0),     W - 1);
            const int xc1 = min(max(x0 + 1, 0), W - 1);
            const int yc0 = min(max(y0, 0),     H - 1);
            const int yc1 = min(max(y0 + 1, 0), H - 1);

            float w00 = a * (1.f - fx) * (1.f - fy);
            float w01 = a * fx * (1.f - fy);
            float w10 = a * (1.f - fx) * fy;
            float w11 = a * fx * fy;
            w00 = (vy0 && vx0) ? w00 : 0.f;
            w01 = (vy0 && vx1) ? w01 : 0.f;
            w10 = (vy1 && vx0) ? w10 : 0.f;
            w11 = (vy1 && vx1) ? w11 : 0.f;

            const uint4 v00 = *(const uint4*)(lthr + ((yc0 * W + xc0) << 6));
            const uint4 v01 = *(const uint4*)(lthr + ((yc0 * W + xc1) << 6));
            const uint4 v10 = *(const uint4*)(lthr + ((yc1 * W + xc0) << 6));
            const uint4 v11 = *(const uint4*)(lthr + ((yc1 * W + xc1) << 6));

            fma8h(acc, w00, v00);
            fma8h(acc, w01, v01);
            fma8h(acc, w10, v10);
            fma8h(acc, w11, v11);
        }
    }

    float* op = out + ((size_t)(b * kQ + q)) * kRow + h * kD + sub * 8;
    float4 r0, r1;
    r0.x = acc[0]; r0.y = acc[1]; r0.z = acc[2]; r0.w = acc[3];
    r1.x = acc[4]; r1.y = acc[5]; r1.z = acc[6]; r1.w = acc[7];
    ((float4*)op)[0] = r0;
    ((float4*)op)[1] = r1;
}

// ---- Fallback: R13 fp32 kernel (proven, used if ws too small) ----
__global__ __launch_bounds__(256, 4) void msda_fwd_f32(
    const float* __restrict__ value,
    const float* __restrict__ loc,
    const float* __restrict__ attw,
    float* __restrict__ out)
{
    const int i    = blockIdx.x;
    const int xcd  = i & 7;
    const int k    = i >> 3;
    const int bpp  = kQ / 32;
    const int b    = (k >= bpp) ? 1 : 0;
    const int j    = k - b * bpp;
    const int h    = xcd;

    __shared__ float lv3[256 * kD];        // 32 KB
    {
        const float* src = value + ((size_t)(b * kLen + kS3)) * kRow + h * kD;
        float4* dst = (float4*)lv3;
        #pragma unroll
        for (int r = 0; r < 8; ++r) {
            const int idx  = r * 256 + threadIdx.x;
            const int pix  = idx >> 3;
            const int quad = idx & 7;
            dst[idx] = *(const float4*)(src + (size_t)pix * kRow + quad * 4);
        }
    }
    __syncthreads();

    const int qi   = threadIdx.x >> 3;
    const int sub  = threadIdx.x & 7;
    const int q    = j * 32 + qi;
    const int g    = (b * kQ + q) * kHd + h;

    const float4* lp4 = (const float4*)(loc  + (size_t)g * 32);
    const float4* ap4 = (const float4*)(attw + (size_t)g * 16);
    const float*  vb  = value + (size_t)b * kLen * kRow + h * kD + sub * 4;

    float4 acc = make_float4(0.f, 0.f, 0.f, 0.f);

    constexpr int Hs[3] = {128, 64, 32};
    constexpr int Ws[3] = {128, 64, 32};
    constexpr int Ss[3] = {0, 16384, 20480};

    #pragma unroll
    for (int l = 0; l < 3; ++l) {
        const int W = Ws[l];
        const int H = Hs[l];
        const int S = Ss[l];

        const float4 lc0 = lp4[2 * l];
        const float4 lc1 = lp4[2 * l + 1];
        const float4 av  = ap4[l];

        const float lx[4] = {lc0.x, lc0.z, lc1.x, lc1.z};
        const float ly[4] = {lc0.y, lc0.w, lc1.y, lc1.w};
        const float aa[4] = {av.x,  av.y,  av.z,  av.w};

        #pragma unroll
        for (int p = 0; p < 4; ++p) {
            const float x = fmaf(lx[p], (float)W, -0.5f);
            const float y = fmaf(ly[p], (float)H, -0.5f);
            const float x0f = floorf(x);
            const float y0f = floorf(y);
            const float fx = x - x0f;
            const float fy = y - y0f;
            const int   x0 = (int)x0f;
            const int   y0 = (int)y0f;
            const float a  = aa[p];

            const bool vx0 = (unsigned)x0       < (unsigned)W;
            const bool vx1 = (unsigned)(x0 + 1) < (unsigned)W;
            const bool vy0 = (unsigned)y0       < (unsigned)H;
            const bool vy1 = (unsigned)(y0 + 1) < (unsigned)H;

            const int xc0 = min(max(x0, 0),     W - 1);
            const int xc1 = min(max(x0 + 1, 0), W - 1);
            const int yc0 = min(max(y0, 0),     H - 1);
            const int yc1 = min(max(y0 + 1, 0), H - 1);

            float w00 = a * (1.f - fx) * (1.f - fy);
            float w01 = a * fx * (1.f - fy);
            float w10 = a * (1.f - fx) * fy;
            float w11 = a * fx * fy;
            w00 = (vy0 && vx0) ? w00 : 0.f;
            w01 = (vy0 && vx1) ? w01 : 0.f;
            w10 = (vy1 && vx0) ? w10 : 0.f;
            w11 = (vy1 && vx1) ? w11 : 0.f;

            const int r0 = (S + yc0 * W) * kRow;
            const int r1 = (S + yc1 * W) * kRow;
            const float4 v00 = *(const float4*)(vb + r0 + xc0 * kRow);
            const float4 v01 = *(const float4*)(vb + r0 + xc1 * kRow);
            const float4 v10 = *(const float4*)(vb + r1 + xc0 * kRow);
            const float4 v11 = *(const float4*)(vb + r1 + xc1 * kRow);

            fma4(acc, w00, v00);
            fma4(acc, w01, v01);
            fma4(acc, w10, v10);
            fma4(acc, w11, v11);
        }
    }

    {
        constexpr int W = 16, H = 16;
        const float4 lc0 = lp4[6];
        const float4 lc1 = lp4[7];
        const float4 av  = ap4[3];

        const float lx[4] = {lc0.x, lc0.z, lc1.x, lc1.z};
        const float ly[4] = {lc0.y, lc0.w, lc1.y, lc1.w};
        const float aa[4] = {av.x,  av.y,  av.z,  av.w};

        #pragma unroll
        for (int p = 0; p < 4; ++p) {
            const float x = fmaf(lx[p], (float)W, -0.5f);
            const float y = fmaf(ly[p], (float)H, -0.5f);
            const float x0f = floorf(x);
            const float y0f = floorf(y);
            const float fx = x - x0f;
            const float fy = y - y0f;
            const int   x0 = (int)x0f;
            const int   y0 = (int)y0f;
            const float a  = aa[p];

            const bool vx0 = (unsigned)x0       < (unsigned)W;
            const bool vx1 = (unsigned)(x0 + 1) < (unsigned)W;
            const bool vy0 = (unsigned)y0       < (unsigned)H;
            const bool vy1 = (unsigned)(y0 + 1) < (unsigned)H;

            const int xc0 = min(max(x0, 0),     W - 1);
            const int xc1 = min(max(x0 + 1, 0), W - 1);
            const int yc0 = min(max(y0, 0),     H - 1);
            const int yc1 = min(max(y0 + 1, 0), H - 1);

            float w00 = a * (1.f - fx) * (1.f - fy);
            float w01 = a * fx * (1.f - fy);
            float w10 = a * (1.f - fx) * fy;
            float w11 = a * fx * fy;
            w00 = (vy0 && vx0) ? w00 : 0.f;
            w01 = (vy0 && vx1) ? w01 : 0.f;
            w10 = (vy1 && vx0) ? w10 : 0.f;
            w11 = (vy1 && vx1) ? w11 : 0.f;

            const float* lbase = lv3 + sub * 4;
            const float4 v00 = *(const float4*)(lbase + (yc0 * W + xc0) * kD);
            const float4 v01 = *(const float4*)(lbase + (yc0 * W + xc1) * kD);
            const float4 v10 = *(const float4*)(lbase + (yc1 * W + xc0) * kD);
            const float4 v11 = *(const float4*)(lbase + (yc1 * W + xc1) * kD);

            fma4(acc, w00, v00);
            fma4(acc, w01, v01);
            fma4(acc, w10, v10);
            fma4(acc, w11, v11);
        }
    }

    *(float4*)(out + ((size_t)(b * kQ + q)) * kRow + h * kD + sub * 4) = acc;
}

extern "C" void kernel_launch(void* const* d_in, const int* in_sizes, int n_in,
                              void* d_out, int out_size, void* d_ws, size_t ws_size,
                              hipStream_t stream) {
    const float* value = (const float*)d_in[0];
    const float* loc   = (const float*)d_in[3];
    const float* attw  = (const float*)d_in[4];
    float* out = (float*)d_out;

    if (ws_size >= kValElems * sizeof(__half)) {
        __half* vh = (__half*)d_ws;
        const int nthr = (int)(kValElems / 4);          // 2,785,280
        cvt_t<<<nthr / 256, 256, 0, stream>>>(value, vh);
        const int grid = kB * kHd * kBlksPerPair;       // 5440
        msda_fwd_h<<<grid, 256, 0, stream>>>(vh, loc, attw, out);
    } else {
        const int grid = kB * kHd * (kQ / 32);          // 10880
        msda_fwd_f32<<<grid, 256, 0, stream>>>(value, loc, attw, out);
    }
}